// Round 8
// baseline (369.297 us; speedup 1.0000x reference)
//
#include <hip/hip_runtime.h>

#define N_N 100000
#define N_E 1600000
#define SLOTS 48           // padded CSR row stride; P(Poisson(16) >= 48) ~ 7e-11
#define N_PAD 100096       // keeps 16B alignment of later regions

#define BK_SHIFT 9
#define BK_SIZE 512                      // nodes per bucket
#define NBKT 196                         // ceil(100000 / 512)
#define MAXB 10240                       // per-bucket edge capacity (mean 8192, +22 sigma)
#define EPB2 16384                       // edges per scatter block
#define NBLK2 ((N_E + EPB2 - 1) / EPB2)  // 98
#define NBLK_EMB 12500                   // emb convert blocks (256 float4 each, exact)
#define NBLK_W 96                        // weight pack blocks

typedef unsigned short ushort_t;
typedef unsigned int uint_t;
typedef __bf16 bf16x8 __attribute__((ext_vector_type(8)));
typedef float f32x4 __attribute__((ext_vector_type(4)));

__device__ __forceinline__ ushort_t f2bf(float f) {   // RNE fp32 -> bf16
    uint_t u = __float_as_uint(f);
    u += 0x7fffu + ((u >> 16) & 1u);
    return (ushort_t)(u >> 16);
}

// pack x as (hi bf16 in low16) | (lo bf16 in high16); x ~= hi + lo to ~16-bit mantissa
__device__ __forceinline__ uint_t pack_hl(float x) {
    uint_t xb = __float_as_uint(x);
    uint_t hb = (xb + 0x7fffu + ((xb >> 16) & 1u)) & 0xffff0000u;
    float rem = x - __uint_as_float(hb);
    uint_t rb = __float_as_uint(rem);
    uint_t lo = (rb + 0x7fffu + ((rb >> 16) & 1u)) >> 16;
    return (hb >> 16) | (lo << 16);
}

__device__ __forceinline__ bf16x8 as_bf16x8(uint4 u) {
    union { uint4 u; bf16x8 v; } c; c.u = u; return c.v;
}

__device__ __forceinline__ void unpack_frag(uint4 p0, uint4 p1, bf16x8& hi, bf16x8& lo) {
    uint4 h, l;
    h.x = (p0.x & 0xffffu) | (p0.y << 16);
    h.y = (p0.z & 0xffffu) | (p0.w << 16);
    h.z = (p1.x & 0xffffu) | (p1.y << 16);
    h.w = (p1.z & 0xffffu) | (p1.w << 16);
    l.x = (p0.x >> 16) | (p0.y & 0xffff0000u);
    l.y = (p0.z >> 16) | (p0.w & 0xffff0000u);
    l.z = (p1.x >> 16) | (p1.y & 0xffff0000u);
    l.w = (p1.z >> 16) | (p1.w & 0xffff0000u);
    hi = as_bf16x8(h); lo = as_bf16x8(l);
}

// ---------------- fused: scatter (blocks 0..97) + emb->bf16 + W pack (rest) ----------------
// pe_dst entry: src (17 bits) | dlocal (9 bits) << 17
__global__ void __launch_bounds__(256) k_scatter_prep(
        const int* __restrict__ src, const int* __restrict__ dst,
        int* __restrict__ cur_d, int* __restrict__ cur_s,
        uint_t* __restrict__ pe_dst, uint_t* __restrict__ pe_src,
        const float* __restrict__ emb, ushort_t* __restrict__ embb,
        const float* __restrict__ W1, const float* __restrict__ W2,
        uint_t* __restrict__ w1pk, uint_t* __restrict__ w2pk) {
    int b = blockIdx.x, t = threadIdx.x;
    if (b >= NBLK2) {
        int pb = b - NBLK2;
        if (pb < NBLK_EMB) {               // emb: 12500*256 float4 = exact
            int i = pb * 256 + t;
            float4 v = ((const float4*)emb)[i];
            ushort4 o;
            o.x = f2bf(v.x); o.y = f2bf(v.y); o.z = f2bf(v.z); o.w = f2bf(v.w);
            ((ushort4*)embb)[i] = o;
        } else {                           // weights: 96*256 = 24576 exact
            int idx = (pb - NBLK_EMB) * 256 + t;
            int j = idx & 7, l = (idx >> 3) & 63;
            int k = (l >> 4) * 8 + j;
            int n = l & 15;
            if (idx < 16384) {
                int kc = (idx >> 9) & 3, nt = idx >> 11;
                w1pk[idx] = pack_hl(W1[(kc * 32 + k) * 128 + nt * 16 + n]);
            } else {
                int i2 = idx - 16384;
                int kc = (i2 >> 9) & 3, nt = i2 >> 11;
                w2pk[i2] = pack_hl(W2[(kc * 32 + k) * 64 + nt * 16 + n]);
            }
        }
        return;
    }
    // ---- scatter ----
    __shared__ int hd[NBKT], hs[NBKT], od[NBKT], os_[NBKT];
    for (int i = t; i < NBKT; i += 256) { hd[i] = 0; hs[i] = 0; }
    __syncthreads();
    int e0 = b * EPB2;
    int eend = min(e0 + EPB2, N_E);
    for (int e = e0 + t; e < eend; e += 256) {
        atomicAdd(&hd[dst[e] >> BK_SHIFT], 1);
        atomicAdd(&hs[src[e] >> BK_SHIFT], 1);
    }
    __syncthreads();
    for (int i = t; i < NBKT; i += 256) {
        int c = hd[i]; od[i]  = c ? atomicAdd(&cur_d[i], c) : 0;
        c = hs[i];     os_[i] = c ? atomicAdd(&cur_s[i], c) : 0;
    }
    __syncthreads();
    for (int i = t; i < NBKT; i += 256) { hd[i] = 0; hs[i] = 0; }
    __syncthreads();
    for (int e = e0 + t; e < eend; e += 256) {   // re-read: window is L2 hot
        int s = src[e], d = dst[e];
        int bd = d >> BK_SHIFT, bs = s >> BK_SHIFT;
        int rd = od[bd]  + atomicAdd(&hd[bd], 1);
        int rs = os_[bs] + atomicAdd(&hs[bs], 1);
        if (rd < MAXB) pe_dst[(size_t)bd * MAXB + rd] = (uint_t)s | ((uint_t)(d & 511) << 17);
        if (rs < MAXB) pe_src[(size_t)bs * MAXB + rs] = (uint_t)s;
    }
}

// ---------------- binC: per-bucket LDS binning -> slots/cnt/nd (dst) and ns (src) ----------------
__global__ void __launch_bounds__(512) k_binC(
        const uint_t* __restrict__ pe_dst, const uint_t* __restrict__ pe_src,
        const int* __restrict__ cur_d, const int* __restrict__ cur_s,
        int* __restrict__ slots, int* __restrict__ cnt,
        float* __restrict__ nd, float* __restrict__ ns) {
    __shared__ int lc[BK_SIZE];
    int t = threadIdx.x, bb = blockIdx.x;
    for (int i = t; i < BK_SIZE; i += 512) lc[i] = 0;
    __syncthreads();
    if (bb < NBKT) {
        int b = bb;
        int cb = min(cur_d[b], MAXB);
        int nbase = b << BK_SHIFT;
        const uint_t* pe = pe_dst + (size_t)b * MAXB;
        for (int e = t; e < cb; e += 512) {
            uint_t ed = pe[e];
            int dloc = (int)(ed >> 17);
            int s = (int)(ed & 0x1ffffu);
            int pos = atomicAdd(&lc[dloc], 1);
            if (pos < SLOTS) slots[(size_t)(nbase + dloc) * SLOTS + pos] = s;
        }
        __syncthreads();
        for (int i = t; i < BK_SIZE; i += 512) {
            int n = nbase + i;
            if (n < N_N) {
                int c = lc[i];
                cnt[n] = c;
                nd[n] = 1.0f / sqrtf((float)max(c, 1));
            }
        }
    } else {
        int b = bb - NBKT;
        int cb = min(cur_s[b], MAXB);
        int nbase = b << BK_SHIFT;
        const uint_t* pe = pe_src + (size_t)b * MAXB;
        for (int e = t; e < cb; e += 512)
            atomicAdd(&lc[(int)pe[e] - nbase], 1);
        __syncthreads();
        for (int i = t; i < BK_SIZE; i += 512) {
            int n = nbase + i;
            if (n < N_N) ns[n] = 1.0f / sqrtf((float)max(lc[i], 1));
        }
    }
}

// ---------------- SpMM layer 1: aggpk[d][f] = packed_hl( nd*sum ns[s]*emb[s][f] ), unroll x8 ----
__global__ void __launch_bounds__(256) k_spmm1(
        const int* __restrict__ cnt, const int* __restrict__ slots,
        const ushort_t* __restrict__ embb, const float* __restrict__ ns,
        const float* __restrict__ nd, uint_t* __restrict__ aggpk) {
    int wid = (blockIdx.x * 256 + (int)threadIdx.x) >> 6;
    int node = __builtin_amdgcn_readfirstlane(wid);
    if (node >= N_N) return;
    int lane = threadIdx.x & 63;
    const int* row = slots + node * SLOTS;
    int len = min(cnt[node], SLOTS);
    float ax0 = 0.f, ay0 = 0.f, ax1 = 0.f, ay1 = 0.f;
    int e = 0;
    int n8 = len & ~7;
    for (; e < n8; e += 8) {
        int s0 = __builtin_amdgcn_readfirstlane(row[e + 0]);
        int s1 = __builtin_amdgcn_readfirstlane(row[e + 1]);
        int s2 = __builtin_amdgcn_readfirstlane(row[e + 2]);
        int s3 = __builtin_amdgcn_readfirstlane(row[e + 3]);
        int s4 = __builtin_amdgcn_readfirstlane(row[e + 4]);
        int s5 = __builtin_amdgcn_readfirstlane(row[e + 5]);
        int s6 = __builtin_amdgcn_readfirstlane(row[e + 6]);
        int s7 = __builtin_amdgcn_readfirstlane(row[e + 7]);
        float w0 = ns[s0], w1 = ns[s1], w2 = ns[s2], w3 = ns[s3];
        float w4 = ns[s4], w5 = ns[s5], w6 = ns[s6], w7 = ns[s7];
        uint_t v0 = ((const uint_t*)(embb + (size_t)s0 * 128))[lane];
        uint_t v1 = ((const uint_t*)(embb + (size_t)s1 * 128))[lane];
        uint_t v2 = ((const uint_t*)(embb + (size_t)s2 * 128))[lane];
        uint_t v3 = ((const uint_t*)(embb + (size_t)s3 * 128))[lane];
        uint_t v4 = ((const uint_t*)(embb + (size_t)s4 * 128))[lane];
        uint_t v5 = ((const uint_t*)(embb + (size_t)s5 * 128))[lane];
        uint_t v6 = ((const uint_t*)(embb + (size_t)s6 * 128))[lane];
        uint_t v7 = ((const uint_t*)(embb + (size_t)s7 * 128))[lane];
        ax0 = fmaf(__uint_as_float(v0 << 16), w0, ax0);
        ay0 = fmaf(__uint_as_float(v0 & 0xffff0000u), w0, ay0);
        ax1 = fmaf(__uint_as_float(v1 << 16), w1, ax1);
        ay1 = fmaf(__uint_as_float(v1 & 0xffff0000u), w1, ay1);
        ax0 = fmaf(__uint_as_float(v2 << 16), w2, ax0);
        ay0 = fmaf(__uint_as_float(v2 & 0xffff0000u), w2, ay0);
        ax1 = fmaf(__uint_as_float(v3 << 16), w3, ax1);
        ay1 = fmaf(__uint_as_float(v3 & 0xffff0000u), w3, ay1);
        ax0 = fmaf(__uint_as_float(v4 << 16), w4, ax0);
        ay0 = fmaf(__uint_as_float(v4 & 0xffff0000u), w4, ay0);
        ax1 = fmaf(__uint_as_float(v5 << 16), w5, ax1);
        ay1 = fmaf(__uint_as_float(v5 & 0xffff0000u), w5, ay1);
        ax0 = fmaf(__uint_as_float(v6 << 16), w6, ax0);
        ay0 = fmaf(__uint_as_float(v6 & 0xffff0000u), w6, ay0);
        ax1 = fmaf(__uint_as_float(v7 << 16), w7, ax1);
        ay1 = fmaf(__uint_as_float(v7 & 0xffff0000u), w7, ay1);
    }
    int n4 = len & ~3;
    for (; e < n4; e += 4) {
        int s0 = __builtin_amdgcn_readfirstlane(row[e + 0]);
        int s1 = __builtin_amdgcn_readfirstlane(row[e + 1]);
        int s2 = __builtin_amdgcn_readfirstlane(row[e + 2]);
        int s3 = __builtin_amdgcn_readfirstlane(row[e + 3]);
        float w0 = ns[s0], w1 = ns[s1], w2 = ns[s2], w3 = ns[s3];
        uint_t v0 = ((const uint_t*)(embb + (size_t)s0 * 128))[lane];
        uint_t v1 = ((const uint_t*)(embb + (size_t)s1 * 128))[lane];
        uint_t v2 = ((const uint_t*)(embb + (size_t)s2 * 128))[lane];
        uint_t v3 = ((const uint_t*)(embb + (size_t)s3 * 128))[lane];
        ax0 = fmaf(__uint_as_float(v0 << 16), w0, ax0);
        ay0 = fmaf(__uint_as_float(v0 & 0xffff0000u), w0, ay0);
        ax1 = fmaf(__uint_as_float(v1 << 16), w1, ax1);
        ay1 = fmaf(__uint_as_float(v1 & 0xffff0000u), w1, ay1);
        ax0 = fmaf(__uint_as_float(v2 << 16), w2, ax0);
        ay0 = fmaf(__uint_as_float(v2 & 0xffff0000u), w2, ay0);
        ax1 = fmaf(__uint_as_float(v3 << 16), w3, ax1);
        ay1 = fmaf(__uint_as_float(v3 & 0xffff0000u), w3, ay1);
    }
    for (; e < len; ++e) {
        int s = __builtin_amdgcn_readfirstlane(row[e]);
        float w = ns[s];
        uint_t v = ((const uint_t*)(embb + (size_t)s * 128))[lane];
        ax0 = fmaf(__uint_as_float(v << 16), w, ax0);
        ay0 = fmaf(__uint_as_float(v & 0xffff0000u), w, ay0);
    }
    float sc = nd[node];
    uint2 o;
    o.x = pack_hl((ax0 + ax1) * sc);   // feat 2*lane
    o.y = pack_hl((ay0 + ay1) * sc);   // feat 2*lane+1
    ((uint2*)(aggpk + (size_t)node * 128))[lane] = o;
}

// ---------------- fused MFMA GEMM: h2b = bf16( relu(agg@W1+b1) @ W2 * ns ) ----------------
#define HST 140
__global__ void __launch_bounds__(256) k_gemm(
        const uint_t* __restrict__ aggpk, const uint_t* __restrict__ w1pk,
        const float* __restrict__ b1, const uint_t* __restrict__ w2pk,
        const float* __restrict__ ns, ushort_t* __restrict__ h2b) {
    __shared__ uint_t sh[64 * HST];
    int t = threadIdx.x;
    int w = t >> 6, l = t & 63;
    int quad = l >> 4, lm = l & 15;
    int nb0 = blockIdx.x * 64;

    f32x4 acc[8];
#pragma unroll
    for (int i = 0; i < 8; i++) acc[i] = (f32x4){0.f, 0.f, 0.f, 0.f};
    const uint_t* abase = aggpk + (size_t)(nb0 + w * 16 + lm) * 128 + quad * 8;
    bf16x8 ahi[4], alo[4];
#pragma unroll
    for (int kc = 0; kc < 4; kc++) {
        uint4 p0 = *(const uint4*)(abase + kc * 32);
        uint4 p1 = *(const uint4*)(abase + kc * 32 + 4);
        unpack_frag(p0, p1, ahi[kc], alo[kc]);
    }
#pragma unroll
    for (int nt = 0; nt < 8; nt++) {
#pragma unroll
        for (int kc = 0; kc < 4; kc++) {
            const uint_t* bb = w1pk + (((nt * 4 + kc) * 64 + l) << 3);
            uint4 q0 = *(const uint4*)(bb);
            uint4 q1 = *(const uint4*)(bb + 4);
            bf16x8 bhi, blo;
            unpack_frag(q0, q1, bhi, blo);
            acc[nt] = __builtin_amdgcn_mfma_f32_16x16x32_bf16(ahi[kc], bhi, acc[nt], 0, 0, 0);
            acc[nt] = __builtin_amdgcn_mfma_f32_16x16x32_bf16(ahi[kc], blo, acc[nt], 0, 0, 0);
            acc[nt] = __builtin_amdgcn_mfma_f32_16x16x32_bf16(alo[kc], bhi, acc[nt], 0, 0, 0);
        }
    }
#pragma unroll
    for (int nt = 0; nt < 8; nt++) {
        float bb = b1[nt * 16 + lm];
#pragma unroll
        for (int r = 0; r < 4; r++) {
            int row = w * 16 + quad * 4 + r;
            float hv = fmaxf(acc[nt][r] + bb, 0.f);
            sh[row * HST + nt * 16 + lm] = pack_hl(hv);
        }
    }
    __syncthreads();

    f32x4 acc2[4];
#pragma unroll
    for (int i = 0; i < 4; i++) acc2[i] = (f32x4){0.f, 0.f, 0.f, 0.f};
    const uint_t* sbase = sh + (w * 16 + lm) * HST + quad * 8;
    bf16x8 hhi[4], hlo[4];
#pragma unroll
    for (int kc = 0; kc < 4; kc++) {
        uint4 p0 = *(const uint4*)(sbase + kc * 32);
        uint4 p1 = *(const uint4*)(sbase + kc * 32 + 4);
        unpack_frag(p0, p1, hhi[kc], hlo[kc]);
    }
#pragma unroll
    for (int nt = 0; nt < 4; nt++) {
#pragma unroll
        for (int kc = 0; kc < 4; kc++) {
            const uint_t* bb = w2pk + (((nt * 4 + kc) * 64 + l) << 3);
            uint4 q0 = *(const uint4*)(bb);
            uint4 q1 = *(const uint4*)(bb + 4);
            bf16x8 bhi, blo;
            unpack_frag(q0, q1, bhi, blo);
            acc2[nt] = __builtin_amdgcn_mfma_f32_16x16x32_bf16(hhi[kc], bhi, acc2[nt], 0, 0, 0);
            acc2[nt] = __builtin_amdgcn_mfma_f32_16x16x32_bf16(hhi[kc], blo, acc2[nt], 0, 0, 0);
            acc2[nt] = __builtin_amdgcn_mfma_f32_16x16x32_bf16(hlo[kc], bhi, acc2[nt], 0, 0, 0);
        }
    }
#pragma unroll
    for (int r = 0; r < 4; r++) {
        int node = nb0 + w * 16 + quad * 4 + r;
        if (node < N_N) {
            float s = ns[node];
#pragma unroll
            for (int nt = 0; nt < 4; nt++)
                h2b[(size_t)node * 64 + nt * 16 + lm] = f2bf(acc2[nt][r] * s);
        }
    }
}

// ---------------- SpMM layer 2: out[d] = nd[d]*sum h2b[s] + b2 ; 2 rows per load instr ----------
__global__ void __launch_bounds__(256) k_spmm2(
        const int* __restrict__ cnt, const int* __restrict__ slots,
        const ushort_t* __restrict__ h2b, const float* __restrict__ nd,
        const float* __restrict__ b2, float* __restrict__ out) {
    int wid = (blockIdx.x * 256 + (int)threadIdx.x) >> 6;
    int node = __builtin_amdgcn_readfirstlane(wid);
    if (node >= N_N) return;
    int lane = threadIdx.x & 63;
    int half = lane >> 5, w32 = lane & 31;
    const int* row = slots + node * SLOTS;
    int len = min(cnt[node], SLOTS);
    const uint_t* H = (const uint_t*)h2b;   // 32 uints per row (2 feats each)
    float a0 = 0.f, a1 = 0.f, b0 = 0.f, b1v = 0.f;
    int e = 0;
    int n8 = len & ~7;
    for (; e < n8; e += 8) {
        int i0 = e + half;
        int s0 = row[i0], s1 = row[i0 + 2], s2 = row[i0 + 4], s3 = row[i0 + 6];
        uint_t v0 = H[(size_t)s0 * 32 + w32];
        uint_t v1 = H[(size_t)s1 * 32 + w32];
        uint_t v2 = H[(size_t)s2 * 32 + w32];
        uint_t v3 = H[(size_t)s3 * 32 + w32];
        a0 += __uint_as_float(v0 << 16); a1 += __uint_as_float(v0 & 0xffff0000u);
        b0 += __uint_as_float(v1 << 16); b1v += __uint_as_float(v1 & 0xffff0000u);
        a0 += __uint_as_float(v2 << 16); a1 += __uint_as_float(v2 & 0xffff0000u);
        b0 += __uint_as_float(v3 << 16); b1v += __uint_as_float(v3 & 0xffff0000u);
    }
    for (; e + 1 < len; e += 2) {
        int s = row[e + half];
        uint_t v = H[(size_t)s * 32 + w32];
        a0 += __uint_as_float(v << 16); a1 += __uint_as_float(v & 0xffff0000u);
    }
    if (e < len && half == 0) {
        int s = row[e];
        uint_t v = H[(size_t)s * 32 + w32];
        a0 += __uint_as_float(v << 16); a1 += __uint_as_float(v & 0xffff0000u);
    }
    a0 += b0; a1 += b1v;
    a0 += __shfl_xor(a0, 32);
    a1 += __shfl_xor(a1, 32);
    if (half == 0) {
        float sc = nd[node];
        float2 bb = ((const float2*)b2)[w32];
        float2 o;
        o.x = a0 * sc + bb.x;
        o.y = a1 * sc + bb.y;
        ((float2*)(out + (size_t)node * 64))[w32] = o;
    }
}

extern "C" void kernel_launch(void* const* d_in, const int* in_sizes, int n_in,
                              void* d_out, int out_size, void* d_ws, size_t ws_size,
                              hipStream_t stream) {
    // inputs: node_ids, src, dst, emb, W1, b1, W2, b2
    const int* src = (const int*)d_in[1];
    const int* dst = (const int*)d_in[2];
    const float* emb = (const float*)d_in[3];
    const float* W1 = (const float*)d_in[4];
    const float* b1 = (const float*)d_in[5];
    const float* W2 = (const float*)d_in[6];
    const float* b2 = (const float*)d_in[7];
    float* out = (float*)d_out;

    // workspace carve (~126 MB)
    int* cur_d   = (int*)d_ws;                               // 256
    int* cur_s   = cur_d + 256;                              // 256
    int* cnt     = cur_s + 256;                              // N_PAD
    float* ns    = (float*)(cnt + N_PAD);                    // N_PAD
    float* nd    = ns + N_PAD;                               // N_PAD
    int* slots   = (int*)(nd + N_PAD);                       // N_N*48         (19.2 MB)
    uint_t* pe_dst = (uint_t*)(slots + (size_t)N_N * SLOTS); // NBKT*MAXB uint ( 8.0 MB)
    uint_t* pe_src = pe_dst + (size_t)NBKT * MAXB;           // NBKT*MAXB uint ( 8.0 MB)
    ushort_t* embb = (ushort_t*)(pe_src + (size_t)NBKT * MAXB); // N_PAD*128 bf16 (25.6 MB)
    uint_t* aggpk = (uint_t*)(embb + (size_t)N_PAD * 128);   // N_PAD*128 u32  (51.2 MB)
    uint_t* w1pk = aggpk + (size_t)N_PAD * 128;              // 16384 (64 KB)
    uint_t* w2pk = w1pk + 16384;                             // 8192  (32 KB)
    ushort_t* h2b = (ushort_t*)(w2pk + 8192);                // N_PAD*64 bf16  (12.8 MB)

    hipMemsetAsync(cur_d, 0, sizeof(int) * 512, stream);
    k_scatter_prep<<<NBLK2 + NBLK_EMB + NBLK_W, 256, 0, stream>>>(
        src, dst, cur_d, cur_s, pe_dst, pe_src, emb, embb, W1, W2, w1pk, w2pk);
    k_binC  <<<2 * NBKT, 512, 0, stream>>>(pe_dst, pe_src, cur_d, cur_s, slots, cnt, nd, ns);
    k_spmm1 <<<(N_N + 3) / 4, 256, 0, stream>>>(cnt, slots, embb, ns, nd, aggpk);
    k_gemm  <<<(N_N + 63) / 64, 256, 0, stream>>>(aggpk, w1pk, b1, w2pk, ns, h2b);
    k_spmm2 <<<(N_N + 3) / 4, 256, 0, stream>>>(cnt, slots, h2b, nd, b2, out);
}

// Round 9
// 321.427 us; speedup vs baseline: 1.1489x; 1.1489x over previous
//
#include <hip/hip_runtime.h>

#define N_N 100000
#define N_E 1600000
#define SLOTS 48           // padded CSR row stride; P(Poisson(16) >= 48) ~ 7e-11
#define N_PAD 100096       // keeps 16B alignment of later regions

#define BK_SHIFT 9
#define BK_SIZE 512                      // nodes per bucket
#define NBKT 196                         // ceil(100000 / 512)
#define MAXB 10240                       // per-bucket edge capacity (mean 8192, +22 sigma)
#define EPB2 4096                        // edges per scatter block
#define NBLK2 ((N_E + EPB2 - 1) / EPB2)  // 391
#define EPT 16                           // edges per scatter thread

// binC+prep fused launch block ranges (512-thread blocks)
#define BINC_BLKS (2 * NBKT)             // 392
#define EMB_BLKS 3125                    // 3.2M float4 / (512 thr * 2)
#define W_BLKS 48                        // 24576 / 512

typedef unsigned short ushort_t;
typedef unsigned int uint_t;
typedef __bf16 bf16x8 __attribute__((ext_vector_type(8)));
typedef float f32x4 __attribute__((ext_vector_type(4)));

__device__ __forceinline__ ushort_t f2bf(float f) {   // RNE fp32 -> bf16
    uint_t u = __float_as_uint(f);
    u += 0x7fffu + ((u >> 16) & 1u);
    return (ushort_t)(u >> 16);
}

// pack x as (hi bf16 in low16) | (lo bf16 in high16); x ~= hi + lo to ~16-bit mantissa
__device__ __forceinline__ uint_t pack_hl(float x) {
    uint_t xb = __float_as_uint(x);
    uint_t hb = (xb + 0x7fffu + ((xb >> 16) & 1u)) & 0xffff0000u;
    float rem = x - __uint_as_float(hb);
    uint_t rb = __float_as_uint(rem);
    uint_t lo = (rb + 0x7fffu + ((rb >> 16) & 1u)) >> 16;
    return (hb >> 16) | (lo << 16);
}

__device__ __forceinline__ bf16x8 as_bf16x8(uint4 u) {
    union { uint4 u; bf16x8 v; } c; c.u = u; return c.v;
}

__device__ __forceinline__ void unpack_frag(uint4 p0, uint4 p1, bf16x8& hi, bf16x8& lo) {
    uint4 h, l;
    h.x = (p0.x & 0xffffu) | (p0.y << 16);
    h.y = (p0.z & 0xffffu) | (p0.w << 16);
    h.z = (p1.x & 0xffffu) | (p1.y << 16);
    h.w = (p1.z & 0xffffu) | (p1.w << 16);
    l.x = (p0.x >> 16) | (p0.y & 0xffff0000u);
    l.y = (p0.z >> 16) | (p0.w & 0xffff0000u);
    l.z = (p1.x >> 16) | (p1.y & 0xffff0000u);
    l.w = (p1.z >> 16) | (p1.w & 0xffff0000u);
    hi = as_bf16x8(h); lo = as_bf16x8(l);
}

// ---------------- scatter: single-pass LDS-rank binning into fixed bucket regions ----------------
// pe_dst entry: src (17 bits) | dlocal (9 bits) << 17
__global__ void __launch_bounds__(256) k_scatter(
        const int* __restrict__ src, const int* __restrict__ dst,
        int* __restrict__ cur_d, int* __restrict__ cur_s,
        uint_t* __restrict__ pe_dst, uint_t* __restrict__ pe_src) {
    __shared__ int hd[NBKT], hs[NBKT], od[NBKT], os_[NBKT];
    int t = threadIdx.x, blk = blockIdx.x;
    for (int i = t; i < NBKT; i += 256) { hd[i] = 0; hs[i] = 0; }
    __syncthreads();
    int e0 = blk * EPB2;
    int myS[EPT], myD[EPT];
    uint_t myR[EPT];
#pragma unroll
    for (int i = 0; i < EPT; i++) {
        int e = e0 + t + i * 256;
        if (e < N_E) {
            int s = src[e], d = dst[e];
            myS[i] = s; myD[i] = d;
            uint_t rd = (uint_t)atomicAdd(&hd[d >> BK_SHIFT], 1);   // rank = old count
            uint_t rs = (uint_t)atomicAdd(&hs[s >> BK_SHIFT], 1);
            myR[i] = rd | (rs << 16);                               // ranks < 4096, fit 16b
        }
    }
    __syncthreads();
    for (int i = t; i < NBKT; i += 256) {
        int c = hd[i]; od[i]  = c ? atomicAdd(&cur_d[i], c) : 0;
        c = hs[i];     os_[i] = c ? atomicAdd(&cur_s[i], c) : 0;
    }
    __syncthreads();
#pragma unroll
    for (int i = 0; i < EPT; i++) {
        int e = e0 + t + i * 256;
        if (e < N_E) {
            int s = myS[i], d = myD[i];
            int rd = od[d >> BK_SHIFT] + (int)(myR[i] & 0xffffu);
            int rs = os_[s >> BK_SHIFT] + (int)(myR[i] >> 16);
            if (rd < MAXB) pe_dst[(size_t)(d >> BK_SHIFT) * MAXB + rd] =
                               (uint_t)s | ((uint_t)(d & 511) << 17);
            if (rs < MAXB) pe_src[(size_t)(s >> BK_SHIFT) * MAXB + rs] = (uint_t)s;
        }
    }
}

// ---------------- fused: binC (blocks 0..391) + emb->bf16 + W pack (backfill blocks) ----------
__global__ void __launch_bounds__(512) k_binC_prep(
        const uint_t* __restrict__ pe_dst, const uint_t* __restrict__ pe_src,
        const int* __restrict__ cur_d, const int* __restrict__ cur_s,
        int* __restrict__ slots, int* __restrict__ cnt,
        float* __restrict__ nd, float* __restrict__ ns,
        const float* __restrict__ emb, ushort_t* __restrict__ embb,
        const float* __restrict__ W1, const float* __restrict__ W2,
        uint_t* __restrict__ w1pk, uint_t* __restrict__ w2pk) {
    int t = threadIdx.x, bb = blockIdx.x;
    if (bb >= BINC_BLKS) {
        int pb = bb - BINC_BLKS;
        if (pb < EMB_BLKS) {                 // emb convert: 2 float4 per thread, exact
            int i = pb * 1024 + t;
            const float4* E4 = (const float4*)emb;
            ushort4* O4 = (ushort4*)embb;
            float4 v0 = E4[i], v1 = E4[i + 512];
            ushort4 o0, o1;
            o0.x = f2bf(v0.x); o0.y = f2bf(v0.y); o0.z = f2bf(v0.z); o0.w = f2bf(v0.w);
            o1.x = f2bf(v1.x); o1.y = f2bf(v1.y); o1.z = f2bf(v1.z); o1.w = f2bf(v1.w);
            O4[i] = o0; O4[i + 512] = o1;
        } else {                              // weight pack: 48*512 = 24576 exact
            int idx = (pb - EMB_BLKS) * 512 + t;
            int j = idx & 7, l = (idx >> 3) & 63;
            int k = (l >> 4) * 8 + j;
            int n = l & 15;
            if (idx < 16384) {
                int kc = (idx >> 9) & 3, nt = idx >> 11;
                w1pk[idx] = pack_hl(W1[(kc * 32 + k) * 128 + nt * 16 + n]);
            } else {
                int i2 = idx - 16384;
                int kc = (i2 >> 9) & 3, nt = i2 >> 11;
                w2pk[i2] = pack_hl(W2[(kc * 32 + k) * 64 + nt * 16 + n]);
            }
        }
        return;
    }
    __shared__ int lc[BK_SIZE];
    for (int i = t; i < BK_SIZE; i += 512) lc[i] = 0;
    __syncthreads();
    if (bb < NBKT) {
        int b = bb;
        int cb = min(cur_d[b], MAXB);
        int nbase = b << BK_SHIFT;
        const uint_t* pe = pe_dst + (size_t)b * MAXB;
        for (int e = t; e < cb; e += 512) {
            uint_t ed = pe[e];
            int dloc = (int)(ed >> 17);
            int s = (int)(ed & 0x1ffffu);
            int pos = atomicAdd(&lc[dloc], 1);
            if (pos < SLOTS) slots[(size_t)(nbase + dloc) * SLOTS + pos] = s;
        }
        __syncthreads();
        for (int i = t; i < BK_SIZE; i += 512) {
            int n = nbase + i;
            if (n < N_N) {
                int c = lc[i];
                cnt[n] = c;
                nd[n] = 1.0f / sqrtf((float)max(c, 1));
            }
        }
    } else {
        int b = bb - NBKT;
        int cb = min(cur_s[b], MAXB);
        int nbase = b << BK_SHIFT;
        const uint_t* pe = pe_src + (size_t)b * MAXB;
        for (int e = t; e < cb; e += 512)
            atomicAdd(&lc[(int)pe[e] - nbase], 1);
        __syncthreads();
        for (int i = t; i < BK_SIZE; i += 512) {
            int n = nbase + i;
            if (n < N_N) ns[n] = 1.0f / sqrtf((float)max(lc[i], 1));
        }
    }
}

// ---------------- SpMM layer 1: aggpk[d][f] = packed_hl( nd*sum ns[s]*emb[s][f] ), unroll x8 ----
__global__ void __launch_bounds__(256) k_spmm1(
        const int* __restrict__ cnt, const int* __restrict__ slots,
        const ushort_t* __restrict__ embb, const float* __restrict__ ns,
        const float* __restrict__ nd, uint_t* __restrict__ aggpk) {
    int wid = (blockIdx.x * 256 + (int)threadIdx.x) >> 6;
    int node = __builtin_amdgcn_readfirstlane(wid);
    if (node >= N_N) return;
    int lane = threadIdx.x & 63;
    const int* row = slots + node * SLOTS;
    int len = min(cnt[node], SLOTS);
    float ax0 = 0.f, ay0 = 0.f, ax1 = 0.f, ay1 = 0.f;
    int e = 0;
    int n8 = len & ~7;
    for (; e < n8; e += 8) {
        int s0 = __builtin_amdgcn_readfirstlane(row[e + 0]);
        int s1 = __builtin_amdgcn_readfirstlane(row[e + 1]);
        int s2 = __builtin_amdgcn_readfirstlane(row[e + 2]);
        int s3 = __builtin_amdgcn_readfirstlane(row[e + 3]);
        int s4 = __builtin_amdgcn_readfirstlane(row[e + 4]);
        int s5 = __builtin_amdgcn_readfirstlane(row[e + 5]);
        int s6 = __builtin_amdgcn_readfirstlane(row[e + 6]);
        int s7 = __builtin_amdgcn_readfirstlane(row[e + 7]);
        float w0 = ns[s0], w1 = ns[s1], w2 = ns[s2], w3 = ns[s3];
        float w4 = ns[s4], w5 = ns[s5], w6 = ns[s6], w7 = ns[s7];
        uint_t v0 = ((const uint_t*)(embb + (size_t)s0 * 128))[lane];
        uint_t v1 = ((const uint_t*)(embb + (size_t)s1 * 128))[lane];
        uint_t v2 = ((const uint_t*)(embb + (size_t)s2 * 128))[lane];
        uint_t v3 = ((const uint_t*)(embb + (size_t)s3 * 128))[lane];
        uint_t v4 = ((const uint_t*)(embb + (size_t)s4 * 128))[lane];
        uint_t v5 = ((const uint_t*)(embb + (size_t)s5 * 128))[lane];
        uint_t v6 = ((const uint_t*)(embb + (size_t)s6 * 128))[lane];
        uint_t v7 = ((const uint_t*)(embb + (size_t)s7 * 128))[lane];
        ax0 = fmaf(__uint_as_float(v0 << 16), w0, ax0);
        ay0 = fmaf(__uint_as_float(v0 & 0xffff0000u), w0, ay0);
        ax1 = fmaf(__uint_as_float(v1 << 16), w1, ax1);
        ay1 = fmaf(__uint_as_float(v1 & 0xffff0000u), w1, ay1);
        ax0 = fmaf(__uint_as_float(v2 << 16), w2, ax0);
        ay0 = fmaf(__uint_as_float(v2 & 0xffff0000u), w2, ay0);
        ax1 = fmaf(__uint_as_float(v3 << 16), w3, ax1);
        ay1 = fmaf(__uint_as_float(v3 & 0xffff0000u), w3, ay1);
        ax0 = fmaf(__uint_as_float(v4 << 16), w4, ax0);
        ay0 = fmaf(__uint_as_float(v4 & 0xffff0000u), w4, ay0);
        ax1 = fmaf(__uint_as_float(v5 << 16), w5, ax1);
        ay1 = fmaf(__uint_as_float(v5 & 0xffff0000u), w5, ay1);
        ax0 = fmaf(__uint_as_float(v6 << 16), w6, ax0);
        ay0 = fmaf(__uint_as_float(v6 & 0xffff0000u), w6, ay0);
        ax1 = fmaf(__uint_as_float(v7 << 16), w7, ax1);
        ay1 = fmaf(__uint_as_float(v7 & 0xffff0000u), w7, ay1);
    }
    int n4 = len & ~3;
    for (; e < n4; e += 4) {
        int s0 = __builtin_amdgcn_readfirstlane(row[e + 0]);
        int s1 = __builtin_amdgcn_readfirstlane(row[e + 1]);
        int s2 = __builtin_amdgcn_readfirstlane(row[e + 2]);
        int s3 = __builtin_amdgcn_readfirstlane(row[e + 3]);
        float w0 = ns[s0], w1 = ns[s1], w2 = ns[s2], w3 = ns[s3];
        uint_t v0 = ((const uint_t*)(embb + (size_t)s0 * 128))[lane];
        uint_t v1 = ((const uint_t*)(embb + (size_t)s1 * 128))[lane];
        uint_t v2 = ((const uint_t*)(embb + (size_t)s2 * 128))[lane];
        uint_t v3 = ((const uint_t*)(embb + (size_t)s3 * 128))[lane];
        ax0 = fmaf(__uint_as_float(v0 << 16), w0, ax0);
        ay0 = fmaf(__uint_as_float(v0 & 0xffff0000u), w0, ay0);
        ax1 = fmaf(__uint_as_float(v1 << 16), w1, ax1);
        ay1 = fmaf(__uint_as_float(v1 & 0xffff0000u), w1, ay1);
        ax0 = fmaf(__uint_as_float(v2 << 16), w2, ax0);
        ay0 = fmaf(__uint_as_float(v2 & 0xffff0000u), w2, ay0);
        ax1 = fmaf(__uint_as_float(v3 << 16), w3, ax1);
        ay1 = fmaf(__uint_as_float(v3 & 0xffff0000u), w3, ay1);
    }
    for (; e < len; ++e) {
        int s = __builtin_amdgcn_readfirstlane(row[e]);
        float w = ns[s];
        uint_t v = ((const uint_t*)(embb + (size_t)s * 128))[lane];
        ax0 = fmaf(__uint_as_float(v << 16), w, ax0);
        ay0 = fmaf(__uint_as_float(v & 0xffff0000u), w, ay0);
    }
    float sc = nd[node];
    uint2 o;
    o.x = pack_hl((ax0 + ax1) * sc);   // feat 2*lane
    o.y = pack_hl((ay0 + ay1) * sc);   // feat 2*lane+1
    ((uint2*)(aggpk + (size_t)node * 128))[lane] = o;
}

// ---------------- fused MFMA GEMM: h2b = bf16( relu(agg@W1+b1) @ W2 * ns ) ----------------
#define HST 140
__global__ void __launch_bounds__(256) k_gemm(
        const uint_t* __restrict__ aggpk, const uint_t* __restrict__ w1pk,
        const float* __restrict__ b1, const uint_t* __restrict__ w2pk,
        const float* __restrict__ ns, ushort_t* __restrict__ h2b) {
    __shared__ uint_t sh[64 * HST];
    int t = threadIdx.x;
    int w = t >> 6, l = t & 63;
    int quad = l >> 4, lm = l & 15;
    int nb0 = blockIdx.x * 64;

    f32x4 acc[8];
#pragma unroll
    for (int i = 0; i < 8; i++) acc[i] = (f32x4){0.f, 0.f, 0.f, 0.f};
    const uint_t* abase = aggpk + (size_t)(nb0 + w * 16 + lm) * 128 + quad * 8;
    bf16x8 ahi[4], alo[4];
#pragma unroll
    for (int kc = 0; kc < 4; kc++) {
        uint4 p0 = *(const uint4*)(abase + kc * 32);
        uint4 p1 = *(const uint4*)(abase + kc * 32 + 4);
        unpack_frag(p0, p1, ahi[kc], alo[kc]);
    }
#pragma unroll
    for (int nt = 0; nt < 8; nt++) {
#pragma unroll
        for (int kc = 0; kc < 4; kc++) {
            const uint_t* bb = w1pk + (((nt * 4 + kc) * 64 + l) << 3);
            uint4 q0 = *(const uint4*)(bb);
            uint4 q1 = *(const uint4*)(bb + 4);
            bf16x8 bhi, blo;
            unpack_frag(q0, q1, bhi, blo);
            acc[nt] = __builtin_amdgcn_mfma_f32_16x16x32_bf16(ahi[kc], bhi, acc[nt], 0, 0, 0);
            acc[nt] = __builtin_amdgcn_mfma_f32_16x16x32_bf16(ahi[kc], blo, acc[nt], 0, 0, 0);
            acc[nt] = __builtin_amdgcn_mfma_f32_16x16x32_bf16(alo[kc], bhi, acc[nt], 0, 0, 0);
        }
    }
#pragma unroll
    for (int nt = 0; nt < 8; nt++) {
        float bb = b1[nt * 16 + lm];
#pragma unroll
        for (int r = 0; r < 4; r++) {
            int row = w * 16 + quad * 4 + r;
            float hv = fmaxf(acc[nt][r] + bb, 0.f);
            sh[row * HST + nt * 16 + lm] = pack_hl(hv);
        }
    }
    __syncthreads();

    f32x4 acc2[4];
#pragma unroll
    for (int i = 0; i < 4; i++) acc2[i] = (f32x4){0.f, 0.f, 0.f, 0.f};
    const uint_t* sbase = sh + (w * 16 + lm) * HST + quad * 8;
    bf16x8 hhi[4], hlo[4];
#pragma unroll
    for (int kc = 0; kc < 4; kc++) {
        uint4 p0 = *(const uint4*)(sbase + kc * 32);
        uint4 p1 = *(const uint4*)(sbase + kc * 32 + 4);
        unpack_frag(p0, p1, hhi[kc], hlo[kc]);
    }
#pragma unroll
    for (int nt = 0; nt < 4; nt++) {
#pragma unroll
        for (int kc = 0; kc < 4; kc++) {
            const uint_t* bb = w2pk + (((nt * 4 + kc) * 64 + l) << 3);
            uint4 q0 = *(const uint4*)(bb);
            uint4 q1 = *(const uint4*)(bb + 4);
            bf16x8 bhi, blo;
            unpack_frag(q0, q1, bhi, blo);
            acc2[nt] = __builtin_amdgcn_mfma_f32_16x16x32_bf16(hhi[kc], bhi, acc2[nt], 0, 0, 0);
            acc2[nt] = __builtin_amdgcn_mfma_f32_16x16x32_bf16(hhi[kc], blo, acc2[nt], 0, 0, 0);
            acc2[nt] = __builtin_amdgcn_mfma_f32_16x16x32_bf16(hlo[kc], bhi, acc2[nt], 0, 0, 0);
        }
    }
#pragma unroll
    for (int r = 0; r < 4; r++) {
        int node = nb0 + w * 16 + quad * 4 + r;
        if (node < N_N) {
            float s = ns[node];
#pragma unroll
            for (int nt = 0; nt < 4; nt++)
                h2b[(size_t)node * 64 + nt * 16 + lm] = f2bf(acc2[nt][r] * s);
        }
    }
}

// ---------------- SpMM layer 2: out[d] = nd[d]*sum h2b[s] + b2 ; 2 rows per load instr ----------
__global__ void __launch_bounds__(256) k_spmm2(
        const int* __restrict__ cnt, const int* __restrict__ slots,
        const ushort_t* __restrict__ h2b, const float* __restrict__ nd,
        const float* __restrict__ b2, float* __restrict__ out) {
    int wid = (blockIdx.x * 256 + (int)threadIdx.x) >> 6;
    int node = __builtin_amdgcn_readfirstlane(wid);
    if (node >= N_N) return;
    int lane = threadIdx.x & 63;
    int half = lane >> 5, w32 = lane & 31;
    const int* row = slots + node * SLOTS;
    int len = min(cnt[node], SLOTS);
    const uint_t* H = (const uint_t*)h2b;   // 32 uints per row (2 feats each)
    float a0 = 0.f, a1 = 0.f, b0 = 0.f, b1v = 0.f;
    int e = 0;
    int n8 = len & ~7;
    for (; e < n8; e += 8) {
        int i0 = e + half;
        int s0 = row[i0], s1 = row[i0 + 2], s2 = row[i0 + 4], s3 = row[i0 + 6];
        uint_t v0 = H[(size_t)s0 * 32 + w32];
        uint_t v1 = H[(size_t)s1 * 32 + w32];
        uint_t v2 = H[(size_t)s2 * 32 + w32];
        uint_t v3 = H[(size_t)s3 * 32 + w32];
        a0 += __uint_as_float(v0 << 16); a1 += __uint_as_float(v0 & 0xffff0000u);
        b0 += __uint_as_float(v1 << 16); b1v += __uint_as_float(v1 & 0xffff0000u);
        a0 += __uint_as_float(v2 << 16); a1 += __uint_as_float(v2 & 0xffff0000u);
        b0 += __uint_as_float(v3 << 16); b1v += __uint_as_float(v3 & 0xffff0000u);
    }
    for (; e + 1 < len; e += 2) {
        int s = row[e + half];
        uint_t v = H[(size_t)s * 32 + w32];
        a0 += __uint_as_float(v << 16); a1 += __uint_as_float(v & 0xffff0000u);
    }
    if (e < len && half == 0) {
        int s = row[e];
        uint_t v = H[(size_t)s * 32 + w32];
        a0 += __uint_as_float(v << 16); a1 += __uint_as_float(v & 0xffff0000u);
    }
    a0 += b0; a1 += b1v;
    a0 += __shfl_xor(a0, 32);
    a1 += __shfl_xor(a1, 32);
    if (half == 0) {
        float sc = nd[node];
        float2 bb = ((const float2*)b2)[w32];
        float2 o;
        o.x = a0 * sc + bb.x;
        o.y = a1 * sc + bb.y;
        ((float2*)(out + (size_t)node * 64))[w32] = o;
    }
}

extern "C" void kernel_launch(void* const* d_in, const int* in_sizes, int n_in,
                              void* d_out, int out_size, void* d_ws, size_t ws_size,
                              hipStream_t stream) {
    // inputs: node_ids, src, dst, emb, W1, b1, W2, b2
    const int* src = (const int*)d_in[1];
    const int* dst = (const int*)d_in[2];
    const float* emb = (const float*)d_in[3];
    const float* W1 = (const float*)d_in[4];
    const float* b1 = (const float*)d_in[5];
    const float* W2 = (const float*)d_in[6];
    const float* b2 = (const float*)d_in[7];
    float* out = (float*)d_out;

    // workspace carve (~126 MB)
    int* cur_d   = (int*)d_ws;                               // 256
    int* cur_s   = cur_d + 256;                              // 256
    int* cnt     = cur_s + 256;                              // N_PAD
    float* ns    = (float*)(cnt + N_PAD);                    // N_PAD
    float* nd    = ns + N_PAD;                               // N_PAD
    int* slots   = (int*)(nd + N_PAD);                       // N_N*48         (19.2 MB)
    uint_t* pe_dst = (uint_t*)(slots + (size_t)N_N * SLOTS); // NBKT*MAXB uint ( 8.0 MB)
    uint_t* pe_src = pe_dst + (size_t)NBKT * MAXB;           // NBKT*MAXB uint ( 8.0 MB)
    ushort_t* embb = (ushort_t*)(pe_src + (size_t)NBKT * MAXB); // N_PAD*128 bf16 (25.6 MB)
    uint_t* aggpk = (uint_t*)(embb + (size_t)N_PAD * 128);   // N_PAD*128 u32  (51.2 MB)
    uint_t* w1pk = aggpk + (size_t)N_PAD * 128;              // 16384 (64 KB)
    uint_t* w2pk = w1pk + 16384;                             // 8192  (32 KB)
    ushort_t* h2b = (ushort_t*)(w2pk + 8192);                // N_PAD*64 bf16  (12.8 MB)

    hipMemsetAsync(cur_d, 0, sizeof(int) * 512, stream);
    k_scatter  <<<NBLK2, 256, 0, stream>>>(src, dst, cur_d, cur_s, pe_dst, pe_src);
    k_binC_prep<<<BINC_BLKS + EMB_BLKS + W_BLKS, 512, 0, stream>>>(
        pe_dst, pe_src, cur_d, cur_s, slots, cnt, nd, ns, emb, embb, W1, W2, w1pk, w2pk);
    k_spmm1 <<<(N_N + 3) / 4, 256, 0, stream>>>(cnt, slots, embb, ns, nd, aggpk);
    k_gemm  <<<(N_N + 63) / 64, 256, 0, stream>>>(aggpk, w1pk, b1, w2pk, ns, h2b);
    k_spmm2 <<<(N_N + 3) / 4, 256, 0, stream>>>(cnt, slots, h2b, nd, b2, out);
}